// Round 1
// baseline (2831.177 us; speedup 1.0000x reference)
//
#include <hip/hip_runtime.h>
#include <hip/hip_bf16.h>
#include <math.h>

#define BATCH 4096
#define NS 26
#define EMBD 106
#define NDF 13
#define SPD (NS * EMBD)        // 2756
#define DIM (SPD + NDF)        // 2769
#define VOCAB 100000
#define NC 4
#define H1N 1024
#define H2N 1024
#define H3N 512

// ---------------- gather: emb lookup + dense concat -> X[B, DIM] ----------------
__global__ void gather_kernel(const int* __restrict__ sparse,
                              const float* __restrict__ dense,
                              const float* __restrict__ tab,
                              float* __restrict__ X) {
    int i = blockIdx.x * blockDim.x + threadIdx.x;
    if (i >= BATCH * DIM) return;
    int b = i / DIM;
    int p = i - b * DIM;
    float v;
    if (p < SPD) {
        int s = p / EMBD;
        int e = p - s * EMBD;
        int row = sparse[b * NS + s];
        v = tab[(size_t)s * (VOCAB * EMBD) + (size_t)row * EMBD + e];
    } else {
        v = dense[b * NDF + (p - SPD)];
    }
    X[i] = v;
}

// ---------------- column stats: mu, rsqrt(var+eps) over R rows ----------------
__global__ void colstats_kernel(const float* __restrict__ X, int C, int R,
                                float* __restrict__ mu, float* __restrict__ rs) {
    // 256 threads = 32 cols x 8 row-groups
    int cx = threadIdx.x & 31;
    int rg = threadIdx.x >> 5;
    int c = blockIdx.x * 32 + cx;
    float s = 0.f, s2 = 0.f;
    if (c < C) {
        for (int r = rg; r < R; r += 8) {
            float v = X[(size_t)r * C + c];
            s += v;
            s2 += v * v;
        }
    }
    __shared__ float ls[8][32], ls2[8][32];
    ls[rg][cx] = s;
    ls2[rg][cx] = s2;
    __syncthreads();
    if (rg == 0 && c < C) {
        float t = 0.f, t2 = 0.f;
        #pragma unroll
        for (int k = 0; k < 8; k++) { t += ls[k][cx]; t2 += ls2[k][cx]; }
        float m = t / (float)R;
        float var = t2 / (float)R - m * m;
        mu[c] = m;
        rs[c] = rsqrtf(var + 1e-5f);
    }
}

// ---------------- elementwise BN apply (+ optional ReLU), in/out may alias ----------------
__global__ void bn_apply_kernel(const float* __restrict__ Xin, float* __restrict__ Xout,
                                const float* __restrict__ mu, const float* __restrict__ rs,
                                int C, int total, int relu) {
    int i = blockIdx.x * blockDim.x + threadIdx.x;
    if (i >= total) return;
    int c = i % C;
    float v = (Xin[i] - mu[c]) * rs[c];
    if (relu) v = fmaxf(v, 0.f);
    Xout[i] = v;
}

// ---------------- cross network + partial final dot (fp32, one block per row) ----------------
__global__ __launch_bounds__(256) void cross_kernel(const float* __restrict__ X0,
                                                    const float* __restrict__ cw,
                                                    const float* __restrict__ cb,
                                                    const float* __restrict__ ow,
                                                    float* __restrict__ logit_cross) {
    int b = blockIdx.x;
    int t = threadIdx.x;
    __shared__ float x0s[DIM];
    __shared__ float xis[DIM];
    __shared__ float red[256];

    for (int j = t; j < DIM; j += 256) {
        float v = X0[(size_t)b * DIM + j];
        x0s[j] = v;
        xis[j] = v;
    }
    __syncthreads();

    for (int l = 0; l < NC; ++l) {
        float p = 0.f;
        for (int j = t; j < DIM; j += 256) p += xis[j] * cw[l * DIM + j];
        red[t] = p;
        __syncthreads();
        for (int s = 128; s > 0; s >>= 1) {
            if (t < s) red[t] += red[t + s];
            __syncthreads();
        }
        float dot = red[0];
        __syncthreads();
        for (int j = t; j < DIM; j += 256)
            xis[j] = x0s[j] * dot + cb[l * DIM + j] + xis[j];
        __syncthreads();
    }

    float p = 0.f;
    for (int j = t; j < DIM; j += 256) p += xis[j] * ow[j];
    red[t] = p;
    __syncthreads();
    for (int s = 128; s > 0; s >>= 1) {
        if (t < s) red[t] += red[t + s];
        __syncthreads();
    }
    if (t == 0) logit_cross[b] = red[0];
}

// ---------------- fp32 SIMT GEMM: C[M,N] = A[M,K] * Bw[K,N]  (64x64 tile, 4x4/thread) ----------------
__global__ __launch_bounds__(256) void gemm_kernel(const float* __restrict__ A,
                                                   const float* __restrict__ Bw,
                                                   float* __restrict__ C,
                                                   int M, int N, int K) {
    __shared__ float As[16][68];   // pad 68: conflict-free stores + 16B-aligned b128 reads
    __shared__ float Bs[16][64];
    const int t = threadIdx.x;
    const int tx = t & 15;   // n-group
    const int ty = t >> 4;   // m-group
    const int m0 = blockIdx.y * 64;
    const int n0 = blockIdx.x * 64;

    const int a_kk = t & 15;
    const int a_mb = t >> 4;   // m = a_mb + 16*i
    const int b_n = t & 63;
    const int b_kb = t >> 6;   // k = b_kb*4 + i

    float acc[4][4];
    #pragma unroll
    for (int i = 0; i < 4; i++)
        #pragma unroll
        for (int j = 0; j < 4; j++) acc[i][j] = 0.f;

    const int nt = (K + 15) >> 4;
    for (int kt = 0; kt < nt; ++kt) {
        const int k0 = kt << 4;
        #pragma unroll
        for (int i = 0; i < 4; i++) {
            int m = a_mb + 16 * i;
            float v = 0.f;
            if (k0 + a_kk < K) v = A[(size_t)(m0 + m) * K + k0 + a_kk];
            As[a_kk][m] = v;
        }
        #pragma unroll
        for (int i = 0; i < 4; i++) {
            int k = b_kb * 4 + i;
            float v = 0.f;
            if (k0 + k < K) v = Bw[(size_t)(k0 + k) * N + n0 + b_n];
            Bs[k][b_n] = v;
        }
        __syncthreads();
        #pragma unroll
        for (int kk = 0; kk < 16; ++kk) {
            float a[4], bb[4];
            #pragma unroll
            for (int i = 0; i < 4; i++) a[i] = As[kk][ty * 4 + i];
            #pragma unroll
            for (int j = 0; j < 4; j++) bb[j] = Bs[kk][tx * 4 + j];
            #pragma unroll
            for (int i = 0; i < 4; i++)
                #pragma unroll
                for (int j = 0; j < 4; j++)
                    acc[i][j] = fmaf(a[i], bb[j], acc[i][j]);
        }
        __syncthreads();
    }
    #pragma unroll
    for (int i = 0; i < 4; i++) {
        int m = m0 + ty * 4 + i;
        #pragma unroll
        for (int j = 0; j < 4; j++)
            C[(size_t)m * N + n0 + tx * 4 + j] = acc[i][j];
    }
}

// ---------------- final: logit = logit_cross + H3 . out_w[DIM:], sigmoid ----------------
__global__ void final_kernel(const float* __restrict__ H3, const float* __restrict__ ow3,
                             const float* __restrict__ lc, float* __restrict__ out) {
    int gw = (blockIdx.x * blockDim.x + threadIdx.x) >> 6;  // one wave per row
    int lane = threadIdx.x & 63;
    if (gw >= BATCH) return;
    float p = 0.f;
    for (int j = lane; j < H3N; j += 64) p += H3[(size_t)gw * H3N + j] * ow3[j];
    #pragma unroll
    for (int off = 32; off > 0; off >>= 1) p += __shfl_down(p, off, 64);
    if (lane == 0) {
        float logit = lc[gw] + p;
        out[gw] = 1.f / (1.f + expf(-logit));
    }
}

extern "C" void kernel_launch(void* const* d_in, const int* in_sizes, int n_in,
                              void* d_out, int out_size, void* d_ws, size_t ws_size,
                              hipStream_t stream) {
    const int* sparse = (const int*)d_in[0];
    const float* dense = (const float*)d_in[1];
    const float* tab = (const float*)d_in[2];
    const float* cw = (const float*)d_in[3];
    const float* cb = (const float*)d_in[4];
    const float* w1 = (const float*)d_in[5];
    // d_in[6] = deep_b1 (zeros; absorbed by BN mean-subtract)
    const float* w2 = (const float*)d_in[7];
    // d_in[8] = deep_b2
    const float* w3 = (const float*)d_in[9];
    // d_in[10] = deep_b3
    const float* ow = (const float*)d_in[11];
    float* out = (float*)d_out;

    // workspace layout (floats)
    float* ws = (float*)d_ws;
    float* X  = ws;                       // BATCH*DIM
    float* mu = X + (size_t)BATCH * DIM;  // 4096
    float* rs = mu + 4096;                // 4096
    float* lc = rs + 4096;                // BATCH
    float* H1 = lc + BATCH;               // BATCH*H1N
    float* H2 = H1 + (size_t)BATCH * H1N; // BATCH*H2N
    float* H3 = H2 + (size_t)BATCH * H2N; // BATCH*H3N

    const int totX = BATCH * DIM;

    // 1. gather + concat
    gather_kernel<<<(totX + 255) / 256, 256, 0, stream>>>(sparse, dense, tab, X);
    // 2. BN(x) -> x0 (in place)
    colstats_kernel<<<(DIM + 31) / 32, 256, 0, stream>>>(X, DIM, BATCH, mu, rs);
    bn_apply_kernel<<<(totX + 255) / 256, 256, 0, stream>>>(X, X, mu, rs, DIM, totX, 0);
    // 3. cross network (fp32) + partial final dot
    cross_kernel<<<BATCH, 256, 0, stream>>>(X, cw, cb, ow, lc);
    // 4. deep layer 1
    gemm_kernel<<<dim3(H1N / 64, BATCH / 64), 256, 0, stream>>>(X, w1, H1, BATCH, H1N, DIM);
    colstats_kernel<<<(H1N + 31) / 32, 256, 0, stream>>>(H1, H1N, BATCH, mu, rs);
    bn_apply_kernel<<<(BATCH * H1N + 255) / 256, 256, 0, stream>>>(H1, H1, mu, rs, H1N, BATCH * H1N, 1);
    // 5. deep layer 2
    gemm_kernel<<<dim3(H2N / 64, BATCH / 64), 256, 0, stream>>>(H1, w2, H2, BATCH, H2N, H1N);
    colstats_kernel<<<(H2N + 31) / 32, 256, 0, stream>>>(H2, H2N, BATCH, mu, rs);
    bn_apply_kernel<<<(BATCH * H2N + 255) / 256, 256, 0, stream>>>(H2, H2, mu, rs, H2N, BATCH * H2N, 1);
    // 6. deep layer 3
    gemm_kernel<<<dim3(H3N / 64, BATCH / 64), 256, 0, stream>>>(H2, w3, H3, BATCH, H3N, H2N);
    colstats_kernel<<<(H3N + 31) / 32, 256, 0, stream>>>(H3, H3N, BATCH, mu, rs);
    bn_apply_kernel<<<(BATCH * H3N + 255) / 256, 256, 0, stream>>>(H3, H3, mu, rs, H3N, BATCH * H3N, 1);
    // 7. final dot + sigmoid
    final_kernel<<<BATCH / 4, 256, 0, stream>>>(H3, ow + DIM, lc, out);
}

// Round 2
// 2061.456 us; speedup vs baseline: 1.3734x; 1.3734x over previous
//
#include <hip/hip_runtime.h>
#include <hip/hip_bf16.h>
#include <math.h>

#define BATCH 4096
#define NS 26
#define EMBD 106
#define NDF 13
#define SPD (NS * EMBD)        // 2756
#define DIM (SPD + NDF)        // 2769
#define KP1 2784               // DIM padded to mult of 32
#define VOCAB 100000
#define NC 4
#define H1N 1024
#define H2N 1024
#define H3N 512

typedef __bf16 bf16;
typedef __attribute__((ext_vector_type(8))) __bf16 bf16x8;
typedef __attribute__((ext_vector_type(4))) float f32x4;

// async global->LDS, 16B per lane; lds ptr must be wave-uniform (HW adds lane*16)
__device__ __forceinline__ void async16(void* lds, const void* g) {
    __builtin_amdgcn_global_load_lds(
        (const __attribute__((address_space(1))) unsigned int*)g,
        (__attribute__((address_space(3))) unsigned int*)lds,
        16, 0, 0);
}

// ---------------- gather: emb lookup + dense concat -> X[B, DIM] fp32 ----------------
__global__ void gather_kernel(const int* __restrict__ sparse,
                              const float* __restrict__ dense,
                              const float* __restrict__ tab,
                              float* __restrict__ X) {
    int i = blockIdx.x * blockDim.x + threadIdx.x;
    if (i >= BATCH * DIM) return;
    int b = i / DIM;
    int p = i - b * DIM;
    float v;
    if (p < SPD) {
        int s = p / EMBD;
        int e = p - s * EMBD;
        int row = sparse[b * NS + s];
        v = tab[(size_t)s * (VOCAB * EMBD) + (size_t)row * EMBD + e];
    } else {
        v = dense[b * NDF + (p - SPD)];
    }
    X[i] = v;
}

// ---------------- column stats over R rows ----------------
__global__ void colstats_kernel(const float* __restrict__ X, int C, int R,
                                float* __restrict__ mu, float* __restrict__ rs) {
    int cx = threadIdx.x & 31;
    int rg = threadIdx.x >> 5;
    int c = blockIdx.x * 32 + cx;
    float s = 0.f, s2 = 0.f;
    if (c < C) {
        for (int r = rg; r < R; r += 8) {
            float v = X[(size_t)r * C + c];
            s += v;
            s2 += v * v;
        }
    }
    __shared__ float ls[8][32], ls2[8][32];
    ls[rg][cx] = s;
    ls2[rg][cx] = s2;
    __syncthreads();
    if (rg == 0 && c < C) {
        float t = 0.f, t2 = 0.f;
        #pragma unroll
        for (int k = 0; k < 8; k++) { t += ls[k][cx]; t2 += ls2[k][cx]; }
        float m = t / (float)R;
        float var = t2 / (float)R - m * m;
        mu[c] = m;
        rs[c] = rsqrtf(var + 1e-5f);
    }
}

// ---------------- BN apply on X: fp32 out (for cross, in-place) + bf16 out padded to KP1 ----------------
__global__ void bn_dual_kernel(const float* __restrict__ Xin, float* __restrict__ Xf,
                               bf16* __restrict__ Xb,
                               const float* __restrict__ mu, const float* __restrict__ rs) {
    int i = blockIdx.x * blockDim.x + threadIdx.x;
    if (i >= BATCH * KP1) return;
    int b = i / KP1;
    int c = i - b * KP1;
    if (c < DIM) {
        float v = (Xin[(size_t)b * DIM + c] - mu[c]) * rs[c];
        Xf[(size_t)b * DIM + c] = v;
        Xb[i] = (bf16)v;
    } else {
        Xb[i] = (bf16)0.f;
    }
}

// ---------------- BN + ReLU -> bf16 (for H1, H2) ----------------
__global__ void bn_relu_bf16_kernel(const float* __restrict__ H, bf16* __restrict__ Hb,
                                    const float* __restrict__ mu, const float* __restrict__ rs,
                                    int C, int total) {
    int i = blockIdx.x * blockDim.x + threadIdx.x;
    if (i >= total) return;
    int c = i % C;
    float v = fmaxf((H[i] - mu[c]) * rs[c], 0.f);
    Hb[i] = (bf16)v;
}

// ---------------- BN + optional ReLU, fp32 in-place (for H3) ----------------
__global__ void bn_apply_kernel(const float* __restrict__ Xin, float* __restrict__ Xout,
                                const float* __restrict__ mu, const float* __restrict__ rs,
                                int C, int total, int relu) {
    int i = blockIdx.x * blockDim.x + threadIdx.x;
    if (i >= total) return;
    int c = i % C;
    float v = (Xin[i] - mu[c]) * rs[c];
    if (relu) v = fmaxf(v, 0.f);
    Xout[i] = v;
}

// ---------------- weight convert + transpose: W[K][N] fp32 -> Wt[N][Kp] bf16 (zero pad) ----------------
__global__ void transpose_bf16_kernel(const float* __restrict__ W, bf16* __restrict__ Wt,
                                      int K, int N, int Kp) {
    __shared__ float tile[32][33];
    int k0 = blockIdx.x * 32, n0 = blockIdx.y * 32;
    int tx = threadIdx.x, ty = threadIdx.y;   // block (32,8)
    for (int r = ty; r < 32; r += 8) {
        int k = k0 + r;
        tile[r][tx] = (k < K) ? W[(size_t)k * N + n0 + tx] : 0.f;
    }
    __syncthreads();
    for (int r = ty; r < 32; r += 8) {
        Wt[(size_t)(n0 + r) * Kp + k0 + tx] = (bf16)tile[tx][r];
    }
}

// ---------------- cross network (fp32) + partial final dot ----------------
__global__ __launch_bounds__(256) void cross_kernel(const float* __restrict__ X0,
                                                    const float* __restrict__ cw,
                                                    const float* __restrict__ cb,
                                                    const float* __restrict__ ow,
                                                    float* __restrict__ logit_cross) {
    int b = blockIdx.x;
    int t = threadIdx.x;
    int lane = t & 63, wid = t >> 6;
    __shared__ float x0s[DIM];
    __shared__ float xis[DIM];
    __shared__ float red[4];

    for (int j = t; j < DIM; j += 256) {
        float v = X0[(size_t)b * DIM + j];
        x0s[j] = v;
        xis[j] = v;
    }
    __syncthreads();

    for (int l = 0; l < NC; ++l) {
        float p = 0.f;
        for (int j = t; j < DIM; j += 256) p += xis[j] * cw[l * DIM + j];
        #pragma unroll
        for (int o = 32; o > 0; o >>= 1) p += __shfl_down(p, o, 64);
        if (lane == 0) red[wid] = p;
        __syncthreads();
        float dot = red[0] + red[1] + red[2] + red[3];
        for (int j = t; j < DIM; j += 256)
            xis[j] = fmaf(x0s[j], dot, cb[l * DIM + j] + xis[j]);
        __syncthreads();
    }

    float p = 0.f;
    for (int j = t; j < DIM; j += 256) p += xis[j] * ow[j];
    #pragma unroll
    for (int o = 32; o > 0; o >>= 1) p += __shfl_down(p, o, 64);
    if (lane == 0) red[wid] = p;
    __syncthreads();
    if (t == 0) logit_cross[b] = red[0] + red[1] + red[2] + red[3];
}

// ---------------- bf16 MFMA GEMM: C[M,N] = A[M,K] * Bt[N,K]^T, fp32 out ----------------
// 128x128 tile, 256 threads (4 waves, 2x2 wave grid, 64x64 per wave = 4x4 MFMA tiles).
// K, lda==ldb==K multiple of 32. M,N multiples of 128.
__global__ __launch_bounds__(256) void mfma_gemm(const bf16* __restrict__ A,
                                                 const bf16* __restrict__ Bt,
                                                 float* __restrict__ C,
                                                 int N, int K) {
    __shared__ __align__(16) bf16 As[128 * 32];
    __shared__ __align__(16) bf16 Bs[128 * 32];
    const int t = threadIdx.x;
    const int wave = t >> 6;
    const int lane = t & 63;
    const int m0 = blockIdx.y * 128;
    const int n0 = blockIdx.x * 128;

    // staging: each wave fills 2 chunks of 1024B in each of As/Bs
    const int ar = lane >> 2;             // row within 16-row chunk
    const int ak = (lane & 3) * 8;        // k element offset (16B)
    const size_t gA0 = (size_t)(m0 + wave * 32 + ar) * K + ak;
    const size_t gA1 = gA0 + (size_t)16 * K;
    const size_t gB0 = (size_t)(n0 + wave * 32 + ar) * K + ak;
    const size_t gB1 = gB0 + (size_t)16 * K;
    bf16* ldsA0 = &As[wave * 1024];       // wave-uniform
    bf16* ldsA1 = &As[wave * 1024 + 512];
    bf16* ldsB0 = &Bs[wave * 1024];
    bf16* ldsB1 = &Bs[wave * 1024 + 512];

    // fragment read coords
    const int wm = (wave & 1) * 64;
    const int wn = (wave >> 1) * 64;
    const int fr = lane & 15;
    const int fk = (lane >> 4) * 8;

    f32x4 acc[4][4] = {};

    const int KT = K >> 5;
    for (int kt = 0; kt < KT; ++kt) {
        const int koff = kt * 32;
        async16(ldsA0, A + gA0 + koff);
        async16(ldsA1, A + gA1 + koff);
        async16(ldsB0, Bt + gB0 + koff);
        async16(ldsB1, Bt + gB1 + koff);
        __syncthreads();   // drains vmcnt before barrier -> staged data visible

        bf16x8 af[4], bfr[4];
        #pragma unroll
        for (int i = 0; i < 4; i++)
            af[i] = *(const bf16x8*)&As[(wm + i * 16 + fr) * 32 + fk];
        #pragma unroll
        for (int j = 0; j < 4; j++)
            bfr[j] = *(const bf16x8*)&Bs[(wn + j * 16 + fr) * 32 + fk];
        #pragma unroll
        for (int i = 0; i < 4; i++)
            #pragma unroll
            for (int j = 0; j < 4; j++)
                acc[i][j] = __builtin_amdgcn_mfma_f32_16x16x32_bf16(af[i], bfr[j], acc[i][j], 0, 0, 0);
        __syncthreads();   // done reading LDS before next stage
    }

    // C/D layout: col = lane&15, row = (lane>>4)*4 + reg
    #pragma unroll
    for (int i = 0; i < 4; i++) {
        int row = m0 + wm + i * 16 + (lane >> 4) * 4;
        #pragma unroll
        for (int j = 0; j < 4; j++) {
            int col = n0 + wn + j * 16 + (lane & 15);
            #pragma unroll
            for (int r = 0; r < 4; r++)
                C[(size_t)(row + r) * N + col] = acc[i][j][r];
        }
    }
}

// ---------------- final: logit = lc + H3 . out_w[DIM:], sigmoid ----------------
__global__ void final_kernel(const float* __restrict__ H3, const float* __restrict__ ow3,
                             const float* __restrict__ lc, float* __restrict__ out) {
    int gw = (blockIdx.x * blockDim.x + threadIdx.x) >> 6;
    int lane = threadIdx.x & 63;
    if (gw >= BATCH) return;
    float p = 0.f;
    for (int j = lane; j < H3N; j += 64) p += H3[(size_t)gw * H3N + j] * ow3[j];
    #pragma unroll
    for (int off = 32; off > 0; off >>= 1) p += __shfl_down(p, off, 64);
    if (lane == 0) {
        float logit = lc[gw] + p;
        out[gw] = 1.f / (1.f + expf(-logit));
    }
}

extern "C" void kernel_launch(void* const* d_in, const int* in_sizes, int n_in,
                              void* d_out, int out_size, void* d_ws, size_t ws_size,
                              hipStream_t stream) {
    const int* sparse = (const int*)d_in[0];
    const float* dense = (const float*)d_in[1];
    const float* tab = (const float*)d_in[2];
    const float* cw = (const float*)d_in[3];
    const float* cb = (const float*)d_in[4];
    const float* w1 = (const float*)d_in[5];
    const float* w2 = (const float*)d_in[7];
    const float* w3 = (const float*)d_in[9];
    const float* ow = (const float*)d_in[11];
    float* out = (float*)d_out;

    // ---- workspace layout ----
    float* ws = (float*)d_ws;
    float* X  = ws;                        // BATCH*DIM
    float* mu = X + (size_t)BATCH * DIM;   // 4096
    float* rs = mu + 4096;                 // 4096
    float* lc = rs + 4096;                 // 4096
    float* H1 = lc + 4096;                 // BATCH*H1N
    float* H2 = H1 + (size_t)BATCH * H1N;  // BATCH*H2N
    float* H3 = H2 + (size_t)BATCH * H2N;  // BATCH*H3N
    bf16* Xb  = (bf16*)(H3 + (size_t)BATCH * H3N);   // BATCH*KP1
    bf16* W1t = Xb + (size_t)BATCH * KP1;            // H1N*KP1
    bf16* W2t = W1t + (size_t)H1N * KP1;             // H2N*H1N
    bf16* W3t = W2t + (size_t)H2N * H1N;             // H3N*H2N
    bf16* H1b = W3t + (size_t)H3N * H2N;             // BATCH*H1N
    bf16* H2b = H1b + (size_t)BATCH * H1N;           // BATCH*H2N

    const int totX = BATCH * DIM;

    // weight convert+transpose (const per call)
    transpose_bf16_kernel<<<dim3(KP1 / 32, H1N / 32), dim3(32, 8), 0, stream>>>(w1, W1t, DIM, H1N, KP1);
    transpose_bf16_kernel<<<dim3(H1N / 32, H2N / 32), dim3(32, 8), 0, stream>>>(w2, W2t, H1N, H2N, H1N);
    transpose_bf16_kernel<<<dim3(H2N / 32, H3N / 32), dim3(32, 8), 0, stream>>>(w3, W3t, H2N, H3N, H2N);

    // 1. gather
    gather_kernel<<<(totX + 255) / 256, 256, 0, stream>>>(sparse, dense, tab, X);
    // 2. BN(x0): fp32 (cross) + bf16 padded (gemm)
    colstats_kernel<<<(DIM + 31) / 32, 256, 0, stream>>>(X, DIM, BATCH, mu, rs);
    bn_dual_kernel<<<(BATCH * KP1 + 255) / 256, 256, 0, stream>>>(X, X, Xb, mu, rs);
    // 3. cross network (fp32)
    cross_kernel<<<BATCH, 256, 0, stream>>>(X, cw, cb, ow, lc);
    // 4. deep layer 1
    mfma_gemm<<<dim3(H1N / 128, BATCH / 128), 256, 0, stream>>>(Xb, W1t, H1, H1N, KP1);
    colstats_kernel<<<(H1N + 31) / 32, 256, 0, stream>>>(H1, H1N, BATCH, mu, rs);
    bn_relu_bf16_kernel<<<(BATCH * H1N + 255) / 256, 256, 0, stream>>>(H1, H1b, mu, rs, H1N, BATCH * H1N);
    // 5. deep layer 2
    mfma_gemm<<<dim3(H2N / 128, BATCH / 128), 256, 0, stream>>>(H1b, W2t, H2, H2N, H1N);
    colstats_kernel<<<(H2N + 31) / 32, 256, 0, stream>>>(H2, H2N, BATCH, mu, rs);
    bn_relu_bf16_kernel<<<(BATCH * H2N + 255) / 256, 256, 0, stream>>>(H2, H2b, mu, rs, H2N, BATCH * H2N);
    // 6. deep layer 3
    mfma_gemm<<<dim3(H3N / 128, BATCH / 128), 256, 0, stream>>>(H2b, W3t, H3, H3N, H2N);
    colstats_kernel<<<(H3N + 31) / 32, 256, 0, stream>>>(H3, H3N, BATCH, mu, rs);
    bn_apply_kernel<<<(BATCH * H3N + 255) / 256, 256, 0, stream>>>(H3, H3, mu, rs, H3N, BATCH * H3N, 1);
    // 7. final dot + sigmoid
    final_kernel<<<BATCH / 4, 256, 0, stream>>>(H3, ow + DIM, lc, out);
}